// Round 1
// baseline (836.644 us; speedup 1.0000x reference)
//
#include <hip/hip_runtime.h>
#include <math.h>

// Problem constants: B=4, C=64, H=W=64 -> HW=4096
#define BATCH 4
#define CH 64
#define HW 4096

// ---------------------------------------------------------------------------
// conv_nc: out[b][n][o] = sum_c W[o][c] * X[b][c][n] + bias[o]   (layout [n][c])
// 4 tasks: 0: XLOW = W_low(x), 1: V = W_value(x), 2: XMID = W_mid(x), 3: XL2 = W_latter(x_latter)
// ---------------------------------------------------------------------------
__global__ __launch_bounds__(256) void conv_nc(
    const float* __restrict__ x, const float* __restrict__ xl,
    const float* __restrict__ Wlow, const float* __restrict__ blow,
    const float* __restrict__ Wval, const float* __restrict__ bval,
    const float* __restrict__ Wmid, const float* __restrict__ bmid,
    const float* __restrict__ Wlat, const float* __restrict__ blat,
    float* __restrict__ XLOW, float* __restrict__ V,
    float* __restrict__ XMID, float* __restrict__ XL2)
{
    const float* X; const float* W; const float* bias; float* out;
    switch (blockIdx.z) {
        case 0: X = x;  W = Wlow; bias = blow; out = XLOW; break;
        case 1: X = x;  W = Wval; bias = bval; out = V;    break;
        case 2: X = x;  W = Wmid; bias = bmid; out = XMID; break;
        default: X = xl; W = Wlat; bias = blat; out = XL2; break;
    }
    int b = blockIdx.y, n0 = blockIdx.x * 64, t = threadIdx.x;
    __shared__ float Wl[64][65];   // [o][c], pad -> conflict-free for lanes over o
    __shared__ float Xl[64][64];   // [c][nl], read broadcast (nl wave-uniform)
    for (int i = t; i < 4096; i += 256) Wl[i >> 6][i & 63] = W[i];
    for (int i = t; i < 4096; i += 256) {
        int c = i >> 6, nl = i & 63;
        Xl[c][nl] = X[(size_t)(b * 64 + c) * HW + n0 + nl];
    }
    __syncthreads();
    int o = t & 63, ng = t >> 6;
    float bo = bias[o];
    for (int k = 0; k < 16; k++) {
        int nl = ng * 16 + k;
        float a0 = bo, a1 = 0.f, a2 = 0.f, a3 = 0.f;
        #pragma unroll
        for (int c = 0; c < 64; c += 4) {
            a0 += Wl[o][c]     * Xl[c][nl];
            a1 += Wl[o][c + 1] * Xl[c + 1][nl];
            a2 += Wl[o][c + 2] * Xl[c + 2][nl];
            a3 += Wl[o][c + 3] * Xl[c + 3][nl];
        }
        out[((size_t)b * HW + n0 + nl) * 64 + o] = (a0 + a1) + (a2 + a3);
    }
}

// ---------------------------------------------------------------------------
// conv_cn: out[b][o][n] = sum_c W[o][c] * X[b][c][n] + bias[o]   (layout [c][n])
// used for XLHI = W_high(x_latter)
// ---------------------------------------------------------------------------
__global__ __launch_bounds__(256) void conv_cn(
    const float* __restrict__ X, const float* __restrict__ W,
    const float* __restrict__ bias, float* __restrict__ out)
{
    int b = blockIdx.y, n0 = blockIdx.x * 64, t = threadIdx.x;
    __shared__ float Wl[64][64];   // [o][c], read broadcast (o wave-uniform)
    __shared__ float Xl[64][64];   // [c][nl], lanes consecutive over nl
    for (int i = t; i < 4096; i += 256) Wl[i >> 6][i & 63] = W[i];
    for (int i = t; i < 4096; i += 256) {
        int c = i >> 6, nl = i & 63;
        Xl[c][nl] = X[(size_t)(b * 64 + c) * HW + n0 + nl];
    }
    __syncthreads();
    int nl = t & 63, og = t >> 6;
    for (int k = 0; k < 16; k++) {
        int o = og * 16 + k;
        float a0 = bias[o], a1 = 0.f, a2 = 0.f, a3 = 0.f;
        #pragma unroll
        for (int c = 0; c < 64; c += 4) {
            a0 += Wl[o][c]     * Xl[c][nl];
            a1 += Wl[o][c + 1] * Xl[c + 1][nl];
            a2 += Wl[o][c + 2] * Xl[c + 2][nl];
            a3 += Wl[o][c + 3] * Xl[c + 3][nl];
        }
        out[((size_t)b * 64 + o) * HW + n0 + nl] = (a0 + a1) + (a2 + a3);
    }
}

// ---------------------------------------------------------------------------
// econv: E2[b][o][n] = sum_c We[o][c] * E1[b][n][c] + be[o]
// ---------------------------------------------------------------------------
__global__ __launch_bounds__(256) void econv(
    const float* __restrict__ E1, const float* __restrict__ W,
    const float* __restrict__ bias, float* __restrict__ E2)
{
    int b = blockIdx.y, n0 = blockIdx.x * 64, t = threadIdx.x;
    __shared__ float Wl[64][64];   // broadcast
    __shared__ float El[64][65];   // [nl][c], pad for lanes over nl
    for (int i = t; i < 4096; i += 256) Wl[i >> 6][i & 63] = W[i];
    for (int i = t; i < 4096; i += 256) {
        int nl = i >> 6, c = i & 63;
        El[nl][c] = E1[((size_t)b * HW + n0 + nl) * 64 + c];
    }
    __syncthreads();
    int nl = t & 63, og = t >> 6;
    for (int k = 0; k < 16; k++) {
        int o = og * 16 + k;
        float a0 = bias[o], a1 = 0.f, a2 = 0.f, a3 = 0.f;
        #pragma unroll
        for (int c = 0; c < 64; c += 4) {
            a0 += Wl[o][c]     * El[nl][c];
            a1 += Wl[o][c + 1] * El[nl][c + 1];
            a2 += Wl[o][c + 2] * El[nl][c + 2];
            a3 += Wl[o][c + 3] * El[nl][c + 3];
        }
        E2[((size_t)b * 64 + o) * HW + n0 + nl] = (a0 + a1) + (a2 + a3);
    }
}

// ---------------------------------------------------------------------------
// stats: per column m, partial max/sum over an n-chunk of 512.
// S[n,m] = sum_c XLOW[n,c] * XLHI[c,m]
// grid: (64 m-tiles, 8 chunks, 4 b), block 256
// ---------------------------------------------------------------------------
__global__ __launch_bounds__(256) void stats_k(
    const float* __restrict__ XLOW, const float* __restrict__ XLHI,
    float* __restrict__ Mp, float* __restrict__ Zp)
{
    int b = blockIdx.z, chunk = blockIdx.y, m0 = blockIdx.x * 64, t = threadIdx.x;
    int ml = t & 63, nl = t >> 6;
    // B column (64 values) in registers; coalesced loads over ml lanes
    float breg[64];
    #pragma unroll
    for (int c = 0; c < 64; c++)
        breg[c] = XLHI[((size_t)b * 64 + c) * HW + m0 + ml];
    __shared__ float Xr[16][64];
    __shared__ float Mr[4][64];
    __shared__ float Zr[4][64];
    float M = -1e30f, Z = 0.f;
    int nbase = chunk * 512;
    for (int blk = 0; blk < 32; blk++) {
        int nb = nbase + blk * 16;
        __syncthreads();
        for (int i = t; i < 1024; i += 256) {
            int r = i >> 6, c = i & 63;
            Xr[r][c] = XLOW[((size_t)b * HW + nb + r) * 64 + c];
        }
        __syncthreads();
        #pragma unroll
        for (int j = 0; j < 4; j++) {
            int r = nl * 4 + j;
            float s0 = 0.f, s1 = 0.f, s2 = 0.f, s3 = 0.f;
            #pragma unroll
            for (int c = 0; c < 64; c += 4) {
                s0 += Xr[r][c]     * breg[c];
                s1 += Xr[r][c + 1] * breg[c + 1];
                s2 += Xr[r][c + 2] * breg[c + 2];
                s3 += Xr[r][c + 3] * breg[c + 3];
            }
            float s = (s0 + s1) + (s2 + s3);
            float Mn = fmaxf(M, s);
            Z = Z * __expf(M - Mn) + __expf(s - Mn);
            M = Mn;
        }
    }
    Mr[nl][ml] = M; Zr[nl][ml] = Z;
    __syncthreads();
    if (t < 64) {
        float Mt = Mr[0][t];
        #pragma unroll
        for (int j = 1; j < 4; j++) Mt = fmaxf(Mt, Mr[j][t]);
        float Zt = 0.f;
        #pragma unroll
        for (int j = 0; j < 4; j++) Zt += Zr[j][t] * __expf(Mr[j][t] - Mt);
        size_t idx = ((size_t)b * 8 + chunk) * HW + m0 + t;
        Mp[idx] = Mt; Zp[idx] = Zt;
    }
}

// merge 8 chunk partials -> M, 1/Z per column
__global__ __launch_bounds__(256) void merge_k(
    const float* __restrict__ Mp, const float* __restrict__ Zp,
    float* __restrict__ Mf, float* __restrict__ Zi)
{
    int gi = blockIdx.x * 256 + threadIdx.x;   // 0 .. 16383
    int b = gi >> 12, m = gi & 4095;
    float M = -1e30f;
    #pragma unroll
    for (int j = 0; j < 8; j++) M = fmaxf(M, Mp[((size_t)b * 8 + j) * HW + m]);
    float Z = 0.f;
    #pragma unroll
    for (int j = 0; j < 8; j++) Z += Zp[((size_t)b * 8 + j) * HW + m] * __expf(Mp[((size_t)b * 8 + j) * HW + m] - M);
    Mf[gi] = M;
    Zi[gi] = 1.f / Z;
}

// ---------------------------------------------------------------------------
// epass: E1[n,c] = sum_m exp(S[n,m]-M[m])/Z[m] * V[m,c] + XLOW[n,c]
// grid: (64 n-tiles, 4 b), block 512 (8 waves, 2/SIMD)
// ---------------------------------------------------------------------------
__global__ __launch_bounds__(512, 2) void epass(
    const float* __restrict__ XLOW, const float* __restrict__ XLHI,
    const float* __restrict__ V, const float* __restrict__ Mf,
    const float* __restrict__ Zi, float* __restrict__ E1)
{
    int b = blockIdx.y, n0 = blockIdx.x * 64, t = threadIdx.x;
    __shared__ float Xr[64][64];   // [n][c] XLOW tile (broadcast reads)
    __shared__ float Vl[64][64];   // [ml][c]
    __shared__ float Wt[64][68];   // weights transposed [ml][n]; 68: f4-aligned, low conflict
    for (int i = t; i < 4096; i += 512) {
        int n = i >> 6, c = i & 63;
        Xr[n][c] = XLOW[((size_t)b * HW + n0 + n) * 64 + c];
    }
    int ml = t & 63, ng = t >> 6;       // phase A mapping (8 groups x 8 rows)
    int nq = t >> 4, clq = t & 15;      // phase B mapping (2n x 4c per thread)
    float acc[2][4];
    #pragma unroll
    for (int i = 0; i < 2; i++)
        #pragma unroll
        for (int j = 0; j < 4; j++) acc[i][j] = 0.f;

    for (int mc = 0; mc < 64; mc++) {
        int m0 = mc * 64;
        __syncthreads();   // protects Vl/Wt from previous phase-B readers; covers Xr on iter 0
        for (int i = t; i < 4096; i += 512) {
            int mm = i >> 6, c = i & 63;
            Vl[mm][c] = V[((size_t)b * HW + m0 + mm) * 64 + c];
        }
        float breg[64];
        #pragma unroll
        for (int c = 0; c < 64; c++)
            breg[c] = XLHI[((size_t)b * 64 + c) * HW + m0 + ml];
        float Mloc = Mf[b * HW + m0 + ml];
        float Zloc = Zi[b * HW + m0 + ml];
        // phase A: compute w = exp(s - M[m]) / Z[m], store transposed
        #pragma unroll
        for (int k = 0; k < 8; k++) {
            int n = ng * 8 + k;
            float s0 = 0.f, s1 = 0.f, s2 = 0.f, s3 = 0.f;
            #pragma unroll
            for (int c = 0; c < 64; c += 4) {
                s0 += Xr[n][c]     * breg[c];
                s1 += Xr[n][c + 1] * breg[c + 1];
                s2 += Xr[n][c + 2] * breg[c + 2];
                s3 += Xr[n][c + 3] * breg[c + 3];
            }
            float s = (s0 + s1) + (s2 + s3);
            Wt[ml][n] = __expf(s - Mloc) * Zloc;
        }
        __syncthreads();
        // phase B: acc[n, c] += sum_ml w[ml][n] * V[ml][c]
        #pragma unroll 8
        for (int mm = 0; mm < 64; mm++) {
            const float2 w = *reinterpret_cast<const float2*>(&Wt[mm][nq * 2]);
            const float4 v = *reinterpret_cast<const float4*>(&Vl[mm][clq * 4]);
            acc[0][0] += w.x * v.x; acc[0][1] += w.x * v.y;
            acc[0][2] += w.x * v.z; acc[0][3] += w.x * v.w;
            acc[1][0] += w.y * v.x; acc[1][1] += w.y * v.y;
            acc[1][2] += w.y * v.z; acc[1][3] += w.y * v.w;
        }
    }
    __syncthreads();
    #pragma unroll
    for (int i = 0; i < 2; i++) {
        int n = nq * 2 + i;
        #pragma unroll
        for (int j = 0; j < 4; j++) {
            int c = clq * 4 + j;
            E1[((size_t)b * HW + n0 + n) * 64 + c] = acc[i][j] + Xr[n][c];
        }
    }
}

// ---------------------------------------------------------------------------
// tmat: T[b][c][d] = sum_n E2[b][c][n] * XL2[b][n][d]
// grid (64 c, 4 b), block 256
// ---------------------------------------------------------------------------
__global__ __launch_bounds__(256) void tmat(
    const float* __restrict__ E2, const float* __restrict__ XL2, float* __restrict__ T)
{
    int b = blockIdx.y, c = blockIdx.x, t = threadIdx.x;
    int d = t & 63, nl = t >> 6;
    const float* e = E2 + ((size_t)b * 64 + c) * HW;
    const float* x2 = XL2 + (size_t)b * HW * 64;
    float acc = 0.f;
    #pragma unroll 8
    for (int k = 0; k < 1024; k++) {
        int n = k * 4 + nl;
        acc += e[n] * x2[(size_t)n * 64 + d];
    }
    __shared__ float red[4][64];
    red[nl][d] = acc;
    __syncthreads();
    if (t < 64) {
        float s = red[0][t] + red[1][t] + red[2][t] + red[3][t];
        T[((size_t)b * 64 + c) * 64 + t] = s;
    }
}

// softmax over c for each (b, d); grid (64 d, 4 b), block 64
__global__ __launch_bounds__(64) void softT(
    const float* __restrict__ T, float* __restrict__ Ts)
{
    int d = blockIdx.x, b = blockIdx.y, c = threadIdx.x;
    float v = T[((size_t)b * 64 + c) * 64 + d];
    float M = v;
    #pragma unroll
    for (int o = 32; o > 0; o >>= 1) M = fmaxf(M, __shfl_xor(M, o, 64));
    float ez = __expf(v - M);
    float Z = ez;
    #pragma unroll
    for (int o = 32; o > 0; o >>= 1) Z += __shfl_xor(Z, o, 64);
    Ts[((size_t)b * 64 + c) * 64 + d] = ez / Z;
}

// out[b][d][n] = sum_c XMID[b][n][c] * Ts[b][c][d]
__global__ __launch_bounds__(256) void outk(
    const float* __restrict__ XMID, const float* __restrict__ Ts, float* __restrict__ out)
{
    int b = blockIdx.y, n0 = blockIdx.x * 64, t = threadIdx.x;
    __shared__ float Xm[64][65];   // [nl][c]
    __shared__ float Tl[64][64];   // [c][d], broadcast reads
    for (int i = t; i < 4096; i += 256) {
        int nl = i >> 6, c = i & 63;
        Xm[nl][c] = XMID[((size_t)b * HW + n0 + nl) * 64 + c];
    }
    for (int i = t; i < 4096; i += 256) Tl[i >> 6][i & 63] = Ts[(size_t)b * 4096 + i];
    __syncthreads();
    int nl = t & 63, dg = t >> 6;
    float accs[16];
    #pragma unroll
    for (int k = 0; k < 16; k++) accs[k] = 0.f;
    for (int c = 0; c < 64; c++) {
        float xv = Xm[nl][c];
        #pragma unroll
        for (int k = 0; k < 16; k++) accs[k] += xv * Tl[c][dg * 16 + k];
    }
    #pragma unroll
    for (int k = 0; k < 16; k++) {
        int d = dg * 16 + k;
        out[((size_t)b * 64 + d) * HW + n0 + nl] = accs[k];
    }
}

// ---------------------------------------------------------------------------
extern "C" void kernel_launch(void* const* d_in, const int* in_sizes, int n_in,
                              void* d_out, int out_size, void* d_ws, size_t ws_size,
                              hipStream_t stream)
{
    const float* x_latter = (const float*)d_in[0];
    const float* x        = (const float*)d_in[1];
    const float* W_high = (const float*)d_in[2];  const float* b_high = (const float*)d_in[3];
    const float* W_low  = (const float*)d_in[4];  const float* b_low  = (const float*)d_in[5];
    const float* W_val  = (const float*)d_in[6];  const float* b_val  = (const float*)d_in[7];
    const float* W_ec   = (const float*)d_in[8];  const float* b_ec   = (const float*)d_in[9];
    const float* W_mid  = (const float*)d_in[10]; const float* b_mid  = (const float*)d_in[11];
    const float* W_lat  = (const float*)d_in[12]; const float* b_lat  = (const float*)d_in[13];
    float* outp = (float*)d_out;

    float* ws = (float*)d_ws;
    size_t off = 0;
    const size_t MAT = (size_t)BATCH * CH * HW;   // 1,048,576 floats
    float* XLHI = ws + off; off += MAT;   // [b][c][m]
    float* XLOW = ws + off; off += MAT;   // [b][n][c]
    float* Vv   = ws + off; off += MAT;   // [b][m][c]
    float* XL2  = ws + off; off += MAT;   // [b][n][d]
    float* XMID = ws + off; off += MAT;   // [b][n][c]
    float* E1   = ws + off; off += MAT;   // [b][n][c]
    float* E2   = ws + off; off += MAT;   // [b][c][n]
    float* Mp   = ws + off; off += (size_t)BATCH * 8 * HW;
    float* Zp   = ws + off; off += (size_t)BATCH * 8 * HW;
    float* Mf   = ws + off; off += (size_t)BATCH * HW;
    float* Zi   = ws + off; off += (size_t)BATCH * HW;
    float* T    = ws + off; off += (size_t)BATCH * 64 * 64;
    float* Ts   = ws + off; off += (size_t)BATCH * 64 * 64;

    conv_nc<<<dim3(64, BATCH, 4), 256, 0, stream>>>(
        x, x_latter, W_low, b_low, W_val, b_val, W_mid, b_mid, W_lat, b_lat,
        XLOW, Vv, XMID, XL2);
    conv_cn<<<dim3(64, BATCH), 256, 0, stream>>>(x_latter, W_high, b_high, XLHI);
    stats_k<<<dim3(64, 8, BATCH), 256, 0, stream>>>(XLOW, XLHI, Mp, Zp);
    merge_k<<<dim3(64), 256, 0, stream>>>(Mp, Zp, Mf, Zi);
    epass<<<dim3(64, BATCH), 512, 0, stream>>>(XLOW, XLHI, Vv, Mf, Zi, E1);
    econv<<<dim3(64, BATCH), 256, 0, stream>>>(E1, W_ec, b_ec, E2);
    tmat<<<dim3(64, BATCH), 256, 0, stream>>>(E2, XL2, T);
    softT<<<dim3(64, BATCH), 64, 0, stream>>>(T, Ts);
    outk<<<dim3(64, BATCH), 256, 0, stream>>>(XMID, Ts, outp);
}

// Round 2
// 310.242 us; speedup vs baseline: 2.6967x; 2.6967x over previous
//
#include <hip/hip_runtime.h>
#include <math.h>

// Problem constants: B=4, C=64, H=W=64 -> HW=4096
#define BATCH 4
#define CH 64
#define HW 4096

typedef __attribute__((ext_vector_type(8))) short short8;
typedef __attribute__((ext_vector_type(4))) float f32x4;

#define MFMA(a, b, c) __builtin_amdgcn_mfma_f32_16x16x32_bf16(a, b, c, 0, 0, 0)

__device__ __forceinline__ short f2bf(float f) {
    unsigned u = __builtin_bit_cast(unsigned, f);
    u += 0x7fffu + ((u >> 16) & 1u);
    return (short)(u >> 16);
}
__device__ __forceinline__ float bf2f(short s) {
    unsigned u = ((unsigned)(unsigned short)s) << 16;
    return __builtin_bit_cast(float, u);
}
// async global->LDS, 16B per lane; lds base must be wave-uniform
__device__ __forceinline__ void gld16(const short* g, short* l) {
    __builtin_amdgcn_global_load_lds(
        (const __attribute__((address_space(1))) unsigned int*)g,
        (__attribute__((address_space(3))) unsigned int*)l, 16, 0, 0);
}

// ---------------------------------------------------------------------------
// convk: 1x1 convs + fragment packing.
// mode (blockIdx.z): 0: XLOW fp32 [b][n][c] + PA (A-frag, row=n,k=c)
//                    1: V -> PVp (B-frag, k=m, col=c)
//                    2: XMID fp32 [b][n][c]
//                    3: XL2  fp32 [b][n][d]
//                    4: XLHI -> PB (B-frag, k=c, col=m)
// ---------------------------------------------------------------------------
__global__ __launch_bounds__(256) void convk(
    const float* __restrict__ x, const float* __restrict__ xl,
    const float* __restrict__ Wlow, const float* __restrict__ blow,
    const float* __restrict__ Wval, const float* __restrict__ bval,
    const float* __restrict__ Wmid, const float* __restrict__ bmid,
    const float* __restrict__ Wlat, const float* __restrict__ blat,
    const float* __restrict__ Whigh, const float* __restrict__ bhigh,
    float* __restrict__ XLOW, float* __restrict__ XMID, float* __restrict__ XL2,
    short* __restrict__ PAh, short* __restrict__ PAl,
    short* __restrict__ PBh, short* __restrict__ PBl,
    short* __restrict__ PVh, short* __restrict__ PVl)
{
    int mode = blockIdx.z;
    const float* X; const float* W; const float* bias;
    switch (mode) {
        case 0:  X = x;  W = Wlow;  bias = blow;  break;
        case 1:  X = x;  W = Wval;  bias = bval;  break;
        case 2:  X = x;  W = Wmid;  bias = bmid;  break;
        case 3:  X = xl; W = Wlat;  bias = blat;  break;
        default: X = xl; W = Whigh; bias = bhigh; break;
    }
    int b = blockIdx.y, n0 = blockIdx.x * 64, t = threadIdx.x;
    __shared__ float Wl[64][65];
    __shared__ float Xl[64][64];
    for (int i = t; i < 4096; i += 256) Wl[i >> 6][i & 63] = W[i];
    for (int i = t; i < 4096; i += 256) {
        int c = i >> 6, nl = i & 63;
        Xl[c][nl] = X[(size_t)(b * 64 + c) * HW + n0 + nl];
    }
    __syncthreads();
    int o = t & 63, ng = t >> 6;
    float bo = bias[o];
    float res[16];
    #pragma unroll
    for (int k = 0; k < 16; k++) {
        int nl = ng * 16 + k;
        float a0 = bo, a1 = 0.f, a2 = 0.f, a3 = 0.f;
        #pragma unroll
        for (int c = 0; c < 64; c += 4) {
            a0 += Wl[o][c]     * Xl[c][nl];
            a1 += Wl[o][c + 1] * Xl[c + 1][nl];
            a2 += Wl[o][c + 2] * Xl[c + 2][nl];
            a3 += Wl[o][c + 3] * Xl[c + 3][nl];
        }
        res[k] = (a0 + a1) + (a2 + a3);
    }
    if (mode == 0) {
        #pragma unroll
        for (int k = 0; k < 16; k++)
            XLOW[((size_t)b * HW + n0 + ng * 16 + k) * 64 + o] = res[k];
        int nt = (n0 >> 4) + ng;
        int kt = o >> 5, g = (o >> 3) & 3, j = o & 7;
        size_t blob = ((size_t)(b * 256 + nt) * 2 + kt) * 512;
        #pragma unroll
        for (int k = 0; k < 16; k++) {
            int lane2 = k + g * 16;
            short h = f2bf(res[k]);
            short l2 = f2bf(res[k] - bf2f(h));
            PAh[blob + lane2 * 8 + j] = h;
            PAl[blob + lane2 * 8 + j] = l2;
        }
    } else if (mode == 1) {
        int ktm = (n0 >> 5) + (ng >> 1);
        int ct = o >> 4;
        size_t blob = ((size_t)(b * 128 + ktm) * 4 + ct) * 512;
        #pragma unroll
        for (int k = 0; k < 16; k++) {
            int g = (ng * 2 + (k >> 3)) & 3, j = k & 7;
            int lane2 = (o & 15) + g * 16;
            short h = f2bf(res[k]);
            short l2 = f2bf(res[k] - bf2f(h));
            PVh[blob + lane2 * 8 + j] = h;
            PVl[blob + lane2 * 8 + j] = l2;
        }
    } else if (mode == 2) {
        #pragma unroll
        for (int k = 0; k < 16; k++)
            XMID[((size_t)b * HW + n0 + ng * 16 + k) * 64 + o] = res[k];
    } else if (mode == 3) {
        #pragma unroll
        for (int k = 0; k < 16; k++)
            XL2[((size_t)b * HW + n0 + ng * 16 + k) * 64 + o] = res[k];
    } else {
        int mt = (n0 >> 4) + ng;
        int kt = o >> 5, g = (o >> 3) & 3, j = o & 7;
        size_t blob = ((size_t)(b * 256 + mt) * 2 + kt) * 512;
        #pragma unroll
        for (int k = 0; k < 16; k++) {
            int lane2 = k + g * 16;
            short h = f2bf(res[k]);
            short l2 = f2bf(res[k] - bf2f(h));
            PBh[blob + lane2 * 8 + j] = h;
            PBl[blob + lane2 * 8 + j] = l2;
        }
    }
}

// ---------------------------------------------------------------------------
// zpass: Z[m] partials = sum_n exp(S[n,m]) over n-chunk of 1024.
// S via split-bf16 MFMA (3-term). grid (64 mchunks, 4 nchunks, 4 b), block 256.
// ---------------------------------------------------------------------------
__global__ __launch_bounds__(256) void zpass(
    const short* __restrict__ PAh, const short* __restrict__ PAl,
    const short* __restrict__ PBh, const short* __restrict__ PBl,
    float* __restrict__ Zp)
{
    int b = blockIdx.z, nc = blockIdx.y, mchunk = blockIdx.x;
    int t = threadIdx.x, wv = t >> 6, ln = t & 63;
    short8 bh[4][2], bl[4][2];
    #pragma unroll
    for (int msub = 0; msub < 4; msub++)
        #pragma unroll
        for (int kt = 0; kt < 2; kt++) {
            size_t o = ((size_t)(b * 256 + mchunk * 4 + msub) * 2 + kt) * 512 + ln * 8;
            bh[msub][kt] = *(const short8*)(PBh + o);
            bl[msub][kt] = *(const short8*)(PBl + o);
        }
    float zacc[4] = {0.f, 0.f, 0.f, 0.f};
    for (int s = 0; s < 16; s++) {
        int nt = nc * 64 + s * 4 + wv;
        size_t ab = ((size_t)(b * 256 + nt) * 2) * 512 + ln * 8;
        short8 ah0 = *(const short8*)(PAh + ab);
        short8 ah1 = *(const short8*)(PAh + ab + 512);
        short8 al0 = *(const short8*)(PAl + ab);
        short8 al1 = *(const short8*)(PAl + ab + 512);
        #pragma unroll
        for (int msub = 0; msub < 4; msub++) {
            f32x4 acc = {0.f, 0.f, 0.f, 0.f};
            acc = MFMA(ah0, bh[msub][0], acc);
            acc = MFMA(ah1, bh[msub][1], acc);
            acc = MFMA(ah0, bl[msub][0], acc);
            acc = MFMA(ah1, bl[msub][1], acc);
            acc = MFMA(al0, bh[msub][0], acc);
            acc = MFMA(al1, bh[msub][1], acc);
            float z = __expf(acc[0]) + __expf(acc[1]) + __expf(acc[2]) + __expf(acc[3]);
            z += __shfl_xor(z, 16, 64);
            z += __shfl_xor(z, 32, 64);
            zacc[msub] += z;
        }
    }
    __shared__ float sZ[4][64];
    if (ln < 16) {
        #pragma unroll
        for (int msub = 0; msub < 4; msub++) sZ[wv][msub * 16 + ln] = zacc[msub];
    }
    __syncthreads();
    if (t < 64) {
        float z = sZ[0][t] + sZ[1][t] + sZ[2][t] + sZ[3][t];
        Zp[((size_t)(b * 4 + nc)) * 4096 + mchunk * 64 + t] = z;
    }
}

__global__ __launch_bounds__(256) void zmerge(
    const float* __restrict__ Zp, float* __restrict__ Zi)
{
    int gi = blockIdx.x * 256 + threadIdx.x;  // 0..16383
    int b = gi >> 12, m = gi & 4095;
    float z = 0.f;
    #pragma unroll
    for (int nc2 = 0; nc2 < 4; nc2++) z += Zp[((size_t)(b * 4 + nc2)) * 4096 + m];
    Zi[gi] = 1.f / z;
}

// ---------------------------------------------------------------------------
// epass2: E1[n,c] = sum_m exp(S[n,m])*Zi[m] * V[m,c] + XLOW[n,c]  (in-place on XLOW)
// grid (64 n-tiles-of-64, 4 b), block 256 (4 waves; wave w owns 16 rows).
// ---------------------------------------------------------------------------
__global__ __launch_bounds__(256) void epass2(
    const short* __restrict__ PAh, const short* __restrict__ PAl,
    const short* __restrict__ PBh, const short* __restrict__ PBl,
    const short* __restrict__ PVh, const short* __restrict__ PVl,
    const float* __restrict__ Zi, float* __restrict__ E1io)
{
    int b = blockIdx.y, nt0 = blockIdx.x;
    int t = threadIdx.x, wv = t >> 6, ln = t & 63;
    __shared__ __align__(16) short sBh[4096], sBl[4096], sVh[4096], sVl[4096];
    __shared__ __align__(16) short sW[4][4][512];  // [wave][kt*2+hl][slot*8+j]

    int nt = nt0 * 4 + wv;
    const size_t abase = ((size_t)(b * 256 + nt) * 2) * 512 + ln * 8;
    const short8 a_h0 = *(const short8*)(PAh + abase);
    const short8 a_h1 = *(const short8*)(PAh + abase + 512);
    const short8 a_l0 = *(const short8*)(PAl + abase);
    const short8 a_l1 = *(const short8*)(PAl + abase + 512);

    f32x4 acc_e[4];
    #pragma unroll
    for (int ct = 0; ct < 4; ct++) acc_e[ct] = (f32x4){0.f, 0.f, 0.f, 0.f};

    for (int mc = 0; mc < 64; mc++) {
        __syncthreads();  // previous iteration's LDS consumers done
        {
            const size_t bb = (size_t)b * 262144 + (size_t)mc * 4096;
            gld16(PBh + bb + t * 8,        sBh + wv * 512);
            gld16(PBh + bb + 2048 + t * 8, sBh + 2048 + wv * 512);
            gld16(PBl + bb + t * 8,        sBl + wv * 512);
            gld16(PBl + bb + 2048 + t * 8, sBl + 2048 + wv * 512);
            gld16(PVh + bb + t * 8,        sVh + wv * 512);
            gld16(PVh + bb + 2048 + t * 8, sVh + 2048 + wv * 512);
            gld16(PVl + bb + t * 8,        sVl + wv * 512);
            gld16(PVl + bb + 2048 + t * 8, sVl + 2048 + wv * 512);
        }
        asm volatile("s_waitcnt vmcnt(0)" ::: "memory");
        __syncthreads();

        // ---- S tiles + w = exp(S)*Zi, written transposed into sW (A-frag layout)
        #pragma unroll
        for (int msub = 0; msub < 4; msub++) {
            const short8 bh0 = *(const short8*)(sBh + (msub * 2 + 0) * 512 + ln * 8);
            const short8 bh1 = *(const short8*)(sBh + (msub * 2 + 1) * 512 + ln * 8);
            const short8 bl0 = *(const short8*)(sBl + (msub * 2 + 0) * 512 + ln * 8);
            const short8 bl1 = *(const short8*)(sBl + (msub * 2 + 1) * 512 + ln * 8);
            f32x4 acc = {0.f, 0.f, 0.f, 0.f};
            acc = MFMA(a_h0, bh0, acc);
            acc = MFMA(a_h1, bh1, acc);
            acc = MFMA(a_h0, bl0, acc);
            acc = MFMA(a_h1, bl1, acc);
            acc = MFMA(a_l0, bh0, acc);
            acc = MFMA(a_l1, bh1, acc);
            float zi = Zi[b * 4096 + mc * 64 + msub * 16 + (ln & 15)];
            #pragma unroll
            for (int r = 0; r < 4; r++) {
                float w = __expf(acc[r]) * zi;
                short wh = f2bf(w);
                short wl = f2bf(w - bf2f(wh));
                int row = (ln >> 4) * 4 + r;
                int m = msub * 16 + (ln & 15);
                int lane2 = row + ((m >> 3) & 3) * 16;
                int slot = lane2 ^ (lane2 >> 3);       // bank-spread swizzle
                int ktw = m >> 5, j = m & 7;
                sW[wv][ktw * 2 + 0][slot * 8 + j] = wh;
                sW[wv][ktw * 2 + 1][slot * 8 + j] = wl;
            }
        }
        // ---- PV: acc_e += w * V   (w from own wave's sW region; no barrier needed)
        int rslot = (ln ^ (ln >> 3)) * 8;
        #pragma unroll
        for (int kt = 0; kt < 2; kt++) {
            const short8 wh = *(const short8*)(&sW[wv][kt * 2 + 0][rslot]);
            const short8 wl = *(const short8*)(&sW[wv][kt * 2 + 1][rslot]);
            #pragma unroll
            for (int ct = 0; ct < 4; ct++) {
                const short8 vh = *(const short8*)(sVh + (kt * 4 + ct) * 512 + ln * 8);
                const short8 vl = *(const short8*)(sVl + (kt * 4 + ct) * 512 + ln * 8);
                acc_e[ct] = MFMA(wh, vh, acc_e[ct]);
                acc_e[ct] = MFMA(wh, vl, acc_e[ct]);
                acc_e[ct] = MFMA(wl, vh, acc_e[ct]);
            }
        }
    }
    // epilogue: add XLOW residual, write E1 (in-place buffer)
    int n0 = nt * 16;
    #pragma unroll
    for (int ct = 0; ct < 4; ct++) {
        #pragma unroll
        for (int r = 0; r < 4; r++) {
            int n = n0 + (ln >> 4) * 4 + r;
            int c = ct * 16 + (ln & 15);
            size_t idx = ((size_t)b * HW + n) * 64 + c;
            E1io[idx] = acc_e[ct][r] + E1io[idx];
        }
    }
}

// ---------------------------------------------------------------------------
// econv: E2[b][o][n] = sum_c We[o][c] * E1[b][n][c] + be[o]
// ---------------------------------------------------------------------------
__global__ __launch_bounds__(256) void econv(
    const float* __restrict__ E1, const float* __restrict__ W,
    const float* __restrict__ bias, float* __restrict__ E2)
{
    int b = blockIdx.y, n0 = blockIdx.x * 64, t = threadIdx.x;
    __shared__ float Wl[64][64];
    __shared__ float El[64][65];
    for (int i = t; i < 4096; i += 256) Wl[i >> 6][i & 63] = W[i];
    for (int i = t; i < 4096; i += 256) {
        int nl = i >> 6, c = i & 63;
        El[nl][c] = E1[((size_t)b * HW + n0 + nl) * 64 + c];
    }
    __syncthreads();
    int nl = t & 63, og = t >> 6;
    for (int k = 0; k < 16; k++) {
        int o = og * 16 + k;
        float a0 = bias[o], a1 = 0.f, a2 = 0.f, a3 = 0.f;
        #pragma unroll
        for (int c = 0; c < 64; c += 4) {
            a0 += Wl[o][c]     * El[nl][c];
            a1 += Wl[o][c + 1] * El[nl][c + 1];
            a2 += Wl[o][c + 2] * El[nl][c + 2];
            a3 += Wl[o][c + 3] * El[nl][c + 3];
        }
        E2[((size_t)b * 64 + o) * HW + n0 + nl] = (a0 + a1) + (a2 + a3);
    }
}

// ---------------------------------------------------------------------------
// tmat: T[b][c][d] = sum_n E2[b][c][n] * XL2[b][n][d]
// ---------------------------------------------------------------------------
__global__ __launch_bounds__(256) void tmat(
    const float* __restrict__ E2, const float* __restrict__ XL2, float* __restrict__ T)
{
    int b = blockIdx.y, c = blockIdx.x, t = threadIdx.x;
    int d = t & 63, nl = t >> 6;
    const float* e = E2 + ((size_t)b * 64 + c) * HW;
    const float* x2 = XL2 + (size_t)b * HW * 64;
    float acc0 = 0.f, acc1 = 0.f;
    #pragma unroll 4
    for (int k = 0; k < 1024; k += 2) {
        int na = k * 4 + nl, nb2 = na + 4;
        acc0 += e[na] * x2[(size_t)na * 64 + d];
        acc1 += e[nb2] * x2[(size_t)nb2 * 64 + d];
    }
    __shared__ float red[4][64];
    red[nl][d] = acc0 + acc1;
    __syncthreads();
    if (t < 64) {
        float s = red[0][t] + red[1][t] + red[2][t] + red[3][t];
        T[((size_t)b * 64 + c) * 64 + t] = s;
    }
}

// softmax over c for each (b, d)
__global__ __launch_bounds__(64) void softT(
    const float* __restrict__ T, float* __restrict__ Ts)
{
    int d = blockIdx.x, b = blockIdx.y, c = threadIdx.x;
    float v = T[((size_t)b * 64 + c) * 64 + d];
    float M = v;
    #pragma unroll
    for (int o = 32; o > 0; o >>= 1) M = fmaxf(M, __shfl_xor(M, o, 64));
    float ez = __expf(v - M);
    float Z = ez;
    #pragma unroll
    for (int o = 32; o > 0; o >>= 1) Z += __shfl_xor(Z, o, 64);
    Ts[((size_t)b * 64 + c) * 64 + d] = ez / Z;
}

// out[b][d][n] = sum_c XMID[b][n][c] * Ts[b][c][d]
__global__ __launch_bounds__(256) void outk(
    const float* __restrict__ XMID, const float* __restrict__ Ts, float* __restrict__ out)
{
    int b = blockIdx.y, n0 = blockIdx.x * 64, t = threadIdx.x;
    __shared__ float Xm[64][65];
    __shared__ float Tl[64][64];
    for (int i = t; i < 4096; i += 256) {
        int nl = i >> 6, c = i & 63;
        Xm[nl][c] = XMID[((size_t)b * HW + n0 + nl) * 64 + c];
    }
    for (int i = t; i < 4096; i += 256) Tl[i >> 6][i & 63] = Ts[(size_t)b * 4096 + i];
    __syncthreads();
    int nl = t & 63, dg = t >> 6;
    float accs[16];
    #pragma unroll
    for (int k = 0; k < 16; k++) accs[k] = 0.f;
    for (int c = 0; c < 64; c++) {
        float xv = Xm[nl][c];
        #pragma unroll
        for (int k = 0; k < 16; k++) accs[k] += xv * Tl[c][dg * 16 + k];
    }
    #pragma unroll
    for (int k = 0; k < 16; k++) {
        int d = dg * 16 + k;
        out[((size_t)b * 64 + d) * HW + n0 + nl] = accs[k];
    }
}

// ---------------------------------------------------------------------------
extern "C" void kernel_launch(void* const* d_in, const int* in_sizes, int n_in,
                              void* d_out, int out_size, void* d_ws, size_t ws_size,
                              hipStream_t stream)
{
    const float* x_latter = (const float*)d_in[0];
    const float* x        = (const float*)d_in[1];
    const float* W_high = (const float*)d_in[2];  const float* b_high = (const float*)d_in[3];
    const float* W_low  = (const float*)d_in[4];  const float* b_low  = (const float*)d_in[5];
    const float* W_val  = (const float*)d_in[6];  const float* b_val  = (const float*)d_in[7];
    const float* W_ec   = (const float*)d_in[8];  const float* b_ec   = (const float*)d_in[9];
    const float* W_mid  = (const float*)d_in[10]; const float* b_mid  = (const float*)d_in[11];
    const float* W_lat  = (const float*)d_in[12]; const float* b_lat  = (const float*)d_in[13];
    float* outp = (float*)d_out;

    const size_t MAT = (size_t)BATCH * CH * HW;  // 1,048,576 elements
    float* ws = (float*)d_ws;
    size_t off = 0;
    float* XLOW = ws + off; off += MAT;              // [b][n][c]; becomes E1 in-place
    float* XMID = ws + off; off += MAT;              // [b][n][c]
    float* XL2  = ws + off; off += MAT;              // [b][n][d]
    float* E2   = ws + off; off += MAT;              // [b][c][n]
    float* Zp   = ws + off; off += (size_t)BATCH * 4 * HW;
    float* Zic  = ws + off; off += (size_t)BATCH * HW;
    float* T    = ws + off; off += (size_t)BATCH * 64 * 64;
    float* Ts   = ws + off; off += (size_t)BATCH * 64 * 64;
    short* sp = (short*)(ws + off);
    short* PAh = sp; sp += MAT;   // packed A-frags of XLOW (hi)
    short* PAl = sp; sp += MAT;
    short* PBh = sp; sp += MAT;   // packed B-frags of XLHI
    short* PBl = sp; sp += MAT;
    short* PVh = sp; sp += MAT;   // packed B-frags of V
    short* PVl = sp; sp += MAT;

    convk<<<dim3(64, BATCH, 5), 256, 0, stream>>>(
        x, x_latter, W_low, b_low, W_val, b_val, W_mid, b_mid, W_lat, b_lat,
        W_high, b_high, XLOW, XMID, XL2, PAh, PAl, PBh, PBl, PVh, PVl);
    zpass<<<dim3(64, 4, BATCH), 256, 0, stream>>>(PAh, PAl, PBh, PBl, Zp);
    zmerge<<<dim3(64), 256, 0, stream>>>(Zp, Zic);
    epass2<<<dim3(64, BATCH), 256, 0, stream>>>(PAh, PAl, PBh, PBl, PVh, PVl, Zic, XLOW);
    econv<<<dim3(64, BATCH), 256, 0, stream>>>(XLOW, W_ec, b_ec, E2);
    tmat<<<dim3(64, BATCH), 256, 0, stream>>>(E2, XL2, T);
    softT<<<dim3(64, BATCH), 64, 0, stream>>>(T, Ts);
    outk<<<dim3(64, BATCH), 256, 0, stream>>>(XMID, Ts, outp);
}

// Round 4
// 211.605 us; speedup vs baseline: 3.9538x; 1.4661x over previous
//
#include <hip/hip_runtime.h>
#include <math.h>

// Problem constants: B=4, C=64, H=W=64 -> HW=4096
#define BATCH 4
#define CH 64
#define HW 4096

typedef __attribute__((ext_vector_type(8))) short short8;
typedef __attribute__((ext_vector_type(4))) float f32x4;

#define MFMA(a, b, c) __builtin_amdgcn_mfma_f32_16x16x32_bf16(a, b, c, 0, 0, 0)

__device__ __forceinline__ short f2bf(float f) {
    unsigned u = __builtin_bit_cast(unsigned, f);
    u += 0x7fffu + ((u >> 16) & 1u);
    return (short)(u >> 16);
}
__device__ __forceinline__ float bf2f(short s) {
    unsigned u = ((unsigned)(unsigned short)s) << 16;
    return __builtin_bit_cast(float, u);
}
// async global->LDS, 16B per lane; lds base must be wave-uniform
__device__ __forceinline__ void gld16(const short* g, short* l) {
    __builtin_amdgcn_global_load_lds(
        (const __attribute__((address_space(1))) unsigned int*)g,
        (__attribute__((address_space(3))) unsigned int*)l, 16, 0, 0);
}

// ---------------------------------------------------------------------------
// convk: 1x1 convs + fragment packing.
// mode: 0 XLOW fp32+PA, 1 V->PV, 2 XMID, 3 XL2, 4 XLHI->PB
// ---------------------------------------------------------------------------
__global__ __launch_bounds__(256) void convk(
    const float* __restrict__ x, const float* __restrict__ xl,
    const float* __restrict__ Wlow, const float* __restrict__ blow,
    const float* __restrict__ Wval, const float* __restrict__ bval,
    const float* __restrict__ Wmid, const float* __restrict__ bmid,
    const float* __restrict__ Wlat, const float* __restrict__ blat,
    const float* __restrict__ Whigh, const float* __restrict__ bhigh,
    float* __restrict__ XLOW, float* __restrict__ XMID, float* __restrict__ XL2,
    short* __restrict__ PAh, short* __restrict__ PAl,
    short* __restrict__ PBh, short* __restrict__ PBl,
    short* __restrict__ PVh, short* __restrict__ PVl)
{
    int mode = blockIdx.z;
    const float* X; const float* W; const float* bias;
    switch (mode) {
        case 0:  X = x;  W = Wlow;  bias = blow;  break;
        case 1:  X = x;  W = Wval;  bias = bval;  break;
        case 2:  X = x;  W = Wmid;  bias = bmid;  break;
        case 3:  X = xl; W = Wlat;  bias = blat;  break;
        default: X = xl; W = Whigh; bias = bhigh; break;
    }
    int b = blockIdx.y, n0 = blockIdx.x * 64, t = threadIdx.x;
    __shared__ float Wl[64][65];
    __shared__ float Xl[64][64];
    for (int i = t; i < 4096; i += 256) Wl[i >> 6][i & 63] = W[i];
    for (int i = t; i < 4096; i += 256) {
        int c = i >> 6, nl = i & 63;
        Xl[c][nl] = X[(size_t)(b * 64 + c) * HW + n0 + nl];
    }
    __syncthreads();
    int o = t & 63, ng = t >> 6;
    float bo = bias[o];
    float res[16];
    #pragma unroll
    for (int k = 0; k < 16; k++) {
        int nl = ng * 16 + k;
        float a0 = bo, a1 = 0.f, a2 = 0.f, a3 = 0.f;
        #pragma unroll
        for (int c = 0; c < 64; c += 4) {
            a0 += Wl[o][c]     * Xl[c][nl];
            a1 += Wl[o][c + 1] * Xl[c + 1][nl];
            a2 += Wl[o][c + 2] * Xl[c + 2][nl];
            a3 += Wl[o][c + 3] * Xl[c + 3][nl];
        }
        res[k] = (a0 + a1) + (a2 + a3);
    }
    if (mode == 0) {
        #pragma unroll
        for (int k = 0; k < 16; k++)
            XLOW[((size_t)b * HW + n0 + ng * 16 + k) * 64 + o] = res[k];
        int nt = (n0 >> 4) + ng;
        int kt = o >> 5, g = (o >> 3) & 3, j = o & 7;
        size_t blob = ((size_t)(b * 256 + nt) * 2 + kt) * 512;
        #pragma unroll
        for (int k = 0; k < 16; k++) {
            int lane2 = k + g * 16;
            short h = f2bf(res[k]);
            short l2 = f2bf(res[k] - bf2f(h));
            PAh[blob + lane2 * 8 + j] = h;
            PAl[blob + lane2 * 8 + j] = l2;
        }
    } else if (mode == 1) {
        int ktm = (n0 >> 5) + (ng >> 1);
        int ct = o >> 4;
        size_t blob = ((size_t)(b * 128 + ktm) * 4 + ct) * 512;
        #pragma unroll
        for (int k = 0; k < 16; k++) {
            int g = (ng * 2 + (k >> 3)) & 3, j = k & 7;
            int lane2 = (o & 15) + g * 16;
            short h = f2bf(res[k]);
            short l2 = f2bf(res[k] - bf2f(h));
            PVh[blob + lane2 * 8 + j] = h;
            PVl[blob + lane2 * 8 + j] = l2;
        }
    } else if (mode == 2) {
        #pragma unroll
        for (int k = 0; k < 16; k++)
            XMID[((size_t)b * HW + n0 + ng * 16 + k) * 64 + o] = res[k];
    } else if (mode == 3) {
        #pragma unroll
        for (int k = 0; k < 16; k++)
            XL2[((size_t)b * HW + n0 + ng * 16 + k) * 64 + o] = res[k];
    } else {
        int mt = (n0 >> 4) + ng;
        int kt = o >> 5, g = (o >> 3) & 3, j = o & 7;
        size_t blob = ((size_t)(b * 256 + mt) * 2 + kt) * 512;
        #pragma unroll
        for (int k = 0; k < 16; k++) {
            int lane2 = k + g * 16;
            short h = f2bf(res[k]);
            short l2 = f2bf(res[k] - bf2f(h));
            PBh[blob + lane2 * 8 + j] = h;
            PBl[blob + lane2 * 8 + j] = l2;
        }
    }
}

// ---------------------------------------------------------------------------
// zpass: Z[m] partials = sum_n exp(S[n,m]) over n-chunk of 1024 (unchanged).
// ---------------------------------------------------------------------------
__global__ __launch_bounds__(256) void zpass(
    const short* __restrict__ PAh, const short* __restrict__ PAl,
    const short* __restrict__ PBh, const short* __restrict__ PBl,
    float* __restrict__ Zp)
{
    int b = blockIdx.z, nc = blockIdx.y, mchunk = blockIdx.x;
    int t = threadIdx.x, wv = t >> 6, ln = t & 63;
    short8 bh[4][2], bl[4][2];
    #pragma unroll
    for (int msub = 0; msub < 4; msub++)
        #pragma unroll
        for (int kt = 0; kt < 2; kt++) {
            size_t o = ((size_t)(b * 256 + mchunk * 4 + msub) * 2 + kt) * 512 + ln * 8;
            bh[msub][kt] = *(const short8*)(PBh + o);
            bl[msub][kt] = *(const short8*)(PBl + o);
        }
    float zacc[4] = {0.f, 0.f, 0.f, 0.f};
    for (int s = 0; s < 16; s++) {
        int nt = nc * 64 + s * 4 + wv;
        size_t ab = ((size_t)(b * 256 + nt) * 2) * 512 + ln * 8;
        short8 ah0 = *(const short8*)(PAh + ab);
        short8 ah1 = *(const short8*)(PAh + ab + 512);
        short8 al0 = *(const short8*)(PAl + ab);
        short8 al1 = *(const short8*)(PAl + ab + 512);
        #pragma unroll
        for (int msub = 0; msub < 4; msub++) {
            f32x4 acc = {0.f, 0.f, 0.f, 0.f};
            acc = MFMA(ah0, bh[msub][0], acc);
            acc = MFMA(ah1, bh[msub][1], acc);
            acc = MFMA(ah0, bl[msub][0], acc);
            acc = MFMA(ah1, bl[msub][1], acc);
            acc = MFMA(al0, bh[msub][0], acc);
            acc = MFMA(al1, bh[msub][1], acc);
            float z = __expf(acc[0]) + __expf(acc[1]) + __expf(acc[2]) + __expf(acc[3]);
            z += __shfl_xor(z, 16, 64);
            z += __shfl_xor(z, 32, 64);
            zacc[msub] += z;
        }
    }
    __shared__ float sZ[4][64];
    if (ln < 16) {
        #pragma unroll
        for (int msub = 0; msub < 4; msub++) sZ[wv][msub * 16 + ln] = zacc[msub];
    }
    __syncthreads();
    if (t < 64) {
        float z = sZ[0][t] + sZ[1][t] + sZ[2][t] + sZ[3][t];
        Zp[((size_t)(b * 4 + nc)) * 4096 + mchunk * 64 + t] = z;
    }
}

__global__ __launch_bounds__(256) void zmerge(
    const float* __restrict__ Zp, float* __restrict__ Zi)
{
    int gi = blockIdx.x * 256 + threadIdx.x;  // 0..16383
    int b = gi >> 12, m = gi & 4095;
    float z = 0.f;
    #pragma unroll
    for (int nc2 = 0; nc2 < 4; nc2++) z += Zp[((size_t)(b * 4 + nc2)) * 4096 + m];
    Zi[gi] = 1.f / z;
}

// ---------------------------------------------------------------------------
// epass3: partial E over an m-segment of 1024.
// grid (16 nblk, 4 mseg, 4 b) = 256 blocks, 512 threads (8 waves).
// Wave owns 2 row-tiles (32 n-rows). 2-buffer LDS pipeline, counted vmcnt,
// barrier-first ordering (write-after-read safe with 2 buffers).
// PV uses R2's proven 3-term split: wh*vh + wh*vl + wl*vh.
// ---------------------------------------------------------------------------
__global__ __launch_bounds__(512) void epass3(
    const short* __restrict__ PAh, const short* __restrict__ PAl,
    const short* __restrict__ PBh, const short* __restrict__ PBl,
    const short* __restrict__ PVh, const short* __restrict__ PVl,
    const float* __restrict__ Zi, float* __restrict__ Ep)
{
    int b = blockIdx.z, mseg = blockIdx.y, nb = blockIdx.x;
    int t = threadIdx.x, wv = t >> 6, ln = t & 63;
    int lnm = ln & 15, lnr = ln >> 4;

    __shared__ __align__(16) short sB[2][2][4096];      // 32 KB [buf][hi/lo]
    __shared__ __align__(16) short sV[2][2][4096];      // 32 KB
    __shared__ __align__(16) short sW[8][2][2][2][512]; // 64 KB [wave][rt][hl][kt]
    __shared__ float sZi[1024];                          // 4 KB

    // A fragments: 2 row-tiles per wave, hi+lo, kt=0/1
    int nt = nb * 16 + wv * 2;
    short8 Ah[2][2], Al[2][2];
    #pragma unroll
    for (int rt = 0; rt < 2; rt++)
        #pragma unroll
        for (int kt = 0; kt < 2; kt++) {
            size_t base = ((size_t)(b * 256 + nt + rt) * 2 + kt) * 512 + ln * 8;
            Ah[rt][kt] = *(const short8*)(PAh + base);
            Al[rt][kt] = *(const short8*)(PAl + base);
        }
    // Zi slice for this m-segment
    sZi[t]       = Zi[b * 4096 + mseg * 1024 + t];
    sZi[t + 512] = Zi[b * 4096 + mseg * 1024 + t + 512];
    __syncthreads();

    f32x4 acc_e[2][4];
    #pragma unroll
    for (int rt = 0; rt < 2; rt++)
        #pragma unroll
        for (int ct = 0; ct < 4; ct++) acc_e[rt][ct] = (f32x4){0.f, 0.f, 0.f, 0.f};

    const int mc0 = mseg * 16;
    // stage tile ii into buffer bufi (4 gld16 per thread)
    #define STAGE(bufi, ii) { \
        size_t bb = (size_t)b * 262144 + (size_t)(mc0 + (ii)) * 4096 + t * 8; \
        gld16(PBh + bb, &sB[bufi][0][wv * 512]); \
        gld16(PBl + bb, &sB[bufi][1][wv * 512]); \
        gld16(PVh + bb, &sV[bufi][0][wv * 512]); \
        gld16(PVl + bb, &sV[bufi][1][wv * 512]); }

    STAGE(0, 0);
    for (int i = 0; i < 16; i++) {
        int cur = i & 1;
        // barrier FIRST: all waves done reading buffer cur^1 before restaging it
        __builtin_amdgcn_s_barrier();
        if (i < 15) {
            STAGE(cur ^ 1, i + 1);
            asm volatile("s_waitcnt vmcnt(4)" ::: "memory");  // cur's 4 loads done
        } else {
            asm volatile("s_waitcnt vmcnt(0)" ::: "memory");
        }
        __builtin_amdgcn_sched_barrier(0);

        // ---- S tiles (3-term) + w = exp(S)*Zi -> sW hi/lo (A-frag layout, swizzled)
        #pragma unroll
        for (int msub = 0; msub < 4; msub++) {
            const short8 bh0 = *(const short8*)&sB[cur][0][(msub * 2 + 0) * 512 + ln * 8];
            const short8 bh1 = *(const short8*)&sB[cur][0][(msub * 2 + 1) * 512 + ln * 8];
            const short8 bl0 = *(const short8*)&sB[cur][1][(msub * 2 + 0) * 512 + ln * 8];
            const short8 bl1 = *(const short8*)&sB[cur][1][(msub * 2 + 1) * 512 + ln * 8];
            float zi = sZi[i * 64 + msub * 16 + lnm];
            int m = msub * 16 + lnm;
            int ktw = m >> 5, j = m & 7, g = (m >> 3) & 3;
            #pragma unroll
            for (int rt = 0; rt < 2; rt++) {
                f32x4 acc = {0.f, 0.f, 0.f, 0.f};
                acc = MFMA(Ah[rt][0], bh0, acc);
                acc = MFMA(Ah[rt][1], bh1, acc);
                acc = MFMA(Ah[rt][0], bl0, acc);
                acc = MFMA(Ah[rt][1], bl1, acc);
                acc = MFMA(Al[rt][0], bh0, acc);
                acc = MFMA(Al[rt][1], bh1, acc);
                #pragma unroll
                for (int r = 0; r < 4; r++) {
                    float w = __expf(acc[r]) * zi;
                    short wh = f2bf(w);
                    short wl2 = f2bf(w - bf2f(wh));
                    int lane2 = (lnr * 4 + r) + g * 16;
                    int slot = lane2 ^ (lane2 >> 3);
                    sW[wv][rt][0][ktw][slot * 8 + j] = wh;
                    sW[wv][rt][1][ktw][slot * 8 + j] = wl2;
                }
            }
        }
        // ---- PV: acc_e += wh*(vh+vl) + wl*vh; V reads shared across both row-tiles
        int rslot = (ln ^ (ln >> 3)) * 8;
        #pragma unroll
        for (int kt = 0; kt < 2; kt++) {
            const short8 w0h = *(const short8*)&sW[wv][0][0][kt][rslot];
            const short8 w0l = *(const short8*)&sW[wv][0][1][kt][rslot];
            const short8 w1h = *(const short8*)&sW[wv][1][0][kt][rslot];
            const short8 w1l = *(const short8*)&sW[wv][1][1][kt][rslot];
            #pragma unroll
            for (int ct = 0; ct < 4; ct++) {
                const short8 vh = *(const short8*)&sV[cur][0][(kt * 4 + ct) * 512 + ln * 8];
                const short8 vl = *(const short8*)&sV[cur][1][(kt * 4 + ct) * 512 + ln * 8];
                acc_e[0][ct] = MFMA(w0h, vh, acc_e[0][ct]);
                acc_e[0][ct] = MFMA(w0h, vl, acc_e[0][ct]);
                acc_e[0][ct] = MFMA(w0l, vh, acc_e[0][ct]);
                acc_e[1][ct] = MFMA(w1h, vh, acc_e[1][ct]);
                acc_e[1][ct] = MFMA(w1h, vl, acc_e[1][ct]);
                acc_e[1][ct] = MFMA(w1l, vh, acc_e[1][ct]);
            }
        }
    }
    #undef STAGE

    // epilogue: write fp32 partials Ep[mseg][b][n][c]
    float* ep = Ep + ((size_t)mseg * BATCH + b) * HW * 64;
    #pragma unroll
    for (int rt = 0; rt < 2; rt++) {
        int n0 = (nt + rt) * 16 + lnr * 4;
        #pragma unroll
        for (int ct = 0; ct < 4; ct++) {
            #pragma unroll
            for (int r = 0; r < 4; r++)
                ep[(size_t)(n0 + r) * 64 + ct * 16 + lnm] = acc_e[rt][ct][r];
        }
    }
}

// ---------------------------------------------------------------------------
// econv5: E1 = sum(4 partials) + XLOW (residual), then E2 = W_ec * E1 + b_ec
// ---------------------------------------------------------------------------
__global__ __launch_bounds__(256) void econv5(
    const float* __restrict__ Ep, const float* __restrict__ XLOW,
    const float* __restrict__ W, const float* __restrict__ bias,
    float* __restrict__ E2)
{
    const size_t SEG = (size_t)BATCH * HW * 64;
    int b = blockIdx.y, n0 = blockIdx.x * 64, t = threadIdx.x;
    __shared__ float Wl[64][64];
    __shared__ float El[64][65];
    for (int i = t; i < 4096; i += 256) Wl[i >> 6][i & 63] = W[i];
    for (int i = t; i < 4096; i += 256) {
        int nl = i >> 6, c = i & 63;
        size_t idx = ((size_t)b * HW + n0 + nl) * 64 + c;
        El[nl][c] = XLOW[idx] + Ep[idx] + Ep[SEG + idx] + Ep[2 * SEG + idx] + Ep[3 * SEG + idx];
    }
    __syncthreads();
    int nl = t & 63, og = t >> 6;
    for (int k = 0; k < 16; k++) {
        int o = og * 16 + k;
        float a0 = bias[o], a1 = 0.f, a2 = 0.f, a3 = 0.f;
        #pragma unroll
        for (int c = 0; c < 64; c += 4) {
            a0 += Wl[o][c]     * El[nl][c];
            a1 += Wl[o][c + 1] * El[nl][c + 1];
            a2 += Wl[o][c + 2] * El[nl][c + 2];
            a3 += Wl[o][c + 3] * El[nl][c + 3];
        }
        E2[((size_t)b * 64 + o) * HW + n0 + nl] = (a0 + a1) + (a2 + a3);
    }
}

// ---------------------------------------------------------------------------
// tmat: T[b][c][d] = sum_n E2[b][c][n] * XL2[b][n][d]; block 1024 (16 n-lanes)
// ---------------------------------------------------------------------------
__global__ __launch_bounds__(1024) void tmat(
    const float* __restrict__ E2, const float* __restrict__ XL2, float* __restrict__ T)
{
    int b = blockIdx.y, c = blockIdx.x, t = threadIdx.x;
    int d = t & 63, nl = t >> 6;   // nl 0..15
    const float* e = E2 + ((size_t)b * 64 + c) * HW;
    const float* x2 = XL2 + (size_t)b * HW * 64;
    float a0 = 0.f, a1 = 0.f;
    #pragma unroll 4
    for (int k = 0; k < 256; k += 2) {
        int na = k * 16 + nl, nb2 = na + 16;
        a0 += e[na] * x2[(size_t)na * 64 + d];
        a1 += e[nb2] * x2[(size_t)nb2 * 64 + d];
    }
    __shared__ float red[16][64];
    red[nl][d] = a0 + a1;
    __syncthreads();
    if (t < 64) {
        float s = 0.f;
        #pragma unroll
        for (int j = 0; j < 16; j++) s += red[j][t];
        T[((size_t)b * 64 + c) * 64 + t] = s;
    }
}

// softmax over c for each (b, d)
__global__ __launch_bounds__(64) void softT(
    const float* __restrict__ T, float* __restrict__ Ts)
{
    int d = blockIdx.x, b = blockIdx.y, c = threadIdx.x;
    float v = T[((size_t)b * 64 + c) * 64 + d];
    float M = v;
    #pragma unroll
    for (int o = 32; o > 0; o >>= 1) M = fmaxf(M, __shfl_xor(M, o, 64));
    float ez = __expf(v - M);
    float Z = ez;
    #pragma unroll
    for (int o = 32; o > 0; o >>= 1) Z += __shfl_xor(Z, o, 64);
    Ts[((size_t)b * 64 + c) * 64 + d] = ez / Z;
}

// out[b][d][n] = sum_c XMID[b][n][c] * Ts[b][c][d]
__global__ __launch_bounds__(256) void outk(
    const float* __restrict__ XMID, const float* __restrict__ Ts, float* __restrict__ out)
{
    int b = blockIdx.y, n0 = blockIdx.x * 64, t = threadIdx.x;
    __shared__ float Xm[64][65];
    __shared__ float Tl[64][64];
    for (int i = t; i < 4096; i += 256) {
        int nl = i >> 6, c = i & 63;
        Xm[nl][c] = XMID[((size_t)b * HW + n0 + nl) * 64 + c];
    }
    for (int i = t; i < 4096; i += 256) Tl[i >> 6][i & 63] = Ts[(size_t)b * 4096 + i];
    __syncthreads();
    int nl = t & 63, dg = t >> 6;
    float accs[16];
    #pragma unroll
    for (int k = 0; k < 16; k++) accs[k] = 0.f;
    for (int c = 0; c < 64; c++) {
        float xv = Xm[nl][c];
        #pragma unroll
        for (int k = 0; k < 16; k++) accs[k] += xv * Tl[c][dg * 16 + k];
    }
    #pragma unroll
    for (int k = 0; k < 16; k++) {
        int d = dg * 16 + k;
        out[((size_t)b * 64 + d) * HW + n0 + nl] = accs[k];
    }
}

// ---------------------------------------------------------------------------
extern "C" void kernel_launch(void* const* d_in, const int* in_sizes, int n_in,
                              void* d_out, int out_size, void* d_ws, size_t ws_size,
                              hipStream_t stream)
{
    const float* x_latter = (const float*)d_in[0];
    const float* x        = (const float*)d_in[1];
    const float* W_high = (const float*)d_in[2];  const float* b_high = (const float*)d_in[3];
    const float* W_low  = (const float*)d_in[4];  const float* b_low  = (const float*)d_in[5];
    const float* W_val  = (const float*)d_in[6];  const float* b_val  = (const float*)d_in[7];
    const float* W_ec   = (const float*)d_in[8];  const float* b_ec   = (const float*)d_in[9];
    const float* W_mid  = (const float*)d_in[10]; const float* b_mid  = (const float*)d_in[11];
    const float* W_lat  = (const float*)d_in[12]; const float* b_lat  = (const float*)d_in[13];
    float* outp = (float*)d_out;

    const size_t MAT = (size_t)BATCH * CH * HW;  // 1,048,576 elements
    float* ws = (float*)d_ws;
    size_t off = 0;
    float* XLOW = ws + off; off += MAT;              // [b][n][c]
    float* XMID = ws + off; off += MAT;              // [b][n][c]
    float* XL2  = ws + off; off += MAT;              // [b][n][d]
    float* Ep   = ws + off; off += 4 * MAT;          // 4 m-segment partials of E
    float* Zp   = ws + off; off += (size_t)BATCH * 4 * HW;
    float* Zic  = ws + off; off += (size_t)BATCH * HW;
    float* T    = ws + off; off += (size_t)BATCH * 64 * 64;
    float* Ts   = ws + off; off += (size_t)BATCH * 64 * 64;
    short* sp = (short*)(ws + off);
    short* PAh = sp; sp += MAT;   // packed A-frags of XLOW (hi)
    short* PAl = sp; sp += MAT;
    short* PBh = sp; sp += MAT;   // packed B-frags of XLHI
    short* PBl = sp; sp += MAT;
    short* PVh = sp; sp += MAT;   // packed B-frags of V
    short* PVl = sp; sp += MAT;
    float* E2  = (float*)PAh;     // alias: PA dead after epass3 (4MB = PAh+PAl)

    convk<<<dim3(64, BATCH, 5), 256, 0, stream>>>(
        x, x_latter, W_low, b_low, W_val, b_val, W_mid, b_mid, W_lat, b_lat,
        W_high, b_high, XLOW, XMID, XL2, PAh, PAl, PBh, PBl, PVh, PVl);
    zpass<<<dim3(64, 4, BATCH), 256, 0, stream>>>(PAh, PAl, PBh, PBl, Zp);
    zmerge<<<dim3(64), 256, 0, stream>>>(Zp, Zic);
    epass3<<<dim3(16, 4, BATCH), 512, 0, stream>>>(PAh, PAl, PBh, PBl, PVh, PVl, Zic, Ep);
    econv5<<<dim3(64, BATCH), 256, 0, stream>>>(Ep, XLOW, W_ec, b_ec, E2);
    tmat<<<dim3(64, BATCH), 1024, 0, stream>>>(E2, XL2, T);
    softT<<<dim3(64, BATCH), 64, 0, stream>>>(T, Ts);
    outk<<<dim3(64, BATCH), 256, 0, stream>>>(XMID, Ts, outp);
}

// Round 5
// 159.649 us; speedup vs baseline: 5.2405x; 1.3254x over previous
//
#include <hip/hip_runtime.h>
#include <math.h>

// Problem constants: B=4, C=64, H=W=64 -> HW=4096
#define BATCH 4
#define CH 64
#define HW 4096

typedef __attribute__((ext_vector_type(8))) short short8;
typedef __attribute__((ext_vector_type(4))) float f32x4;
typedef __attribute__((ext_vector_type(4))) float float4v;

#define MFMA(a, b, c) __builtin_amdgcn_mfma_f32_16x16x32_bf16(a, b, c, 0, 0, 0)

__device__ __forceinline__ short f2bf(float f) {
    unsigned u = __builtin_bit_cast(unsigned, f);
    u += 0x7fffu + ((u >> 16) & 1u);
    return (short)(u >> 16);
}
__device__ __forceinline__ float bf2f(short s) {
    unsigned u = ((unsigned)(unsigned short)s) << 16;
    return __builtin_bit_cast(float, u);
}
// async global->LDS, 16B per lane; lds base must be wave-uniform
__device__ __forceinline__ void gld16(const short* g, short* l) {
    __builtin_amdgcn_global_load_lds(
        (const __attribute__((address_space(1))) unsigned int*)g,
        (__attribute__((address_space(3))) unsigned int*)l, 16, 0, 0);
}

// ---------------------------------------------------------------------------
// splitX: pre-split x / x_latter into bf16 hi/lo B-frag blobs.
// Blob layout (matches PB/conv-B convention):
//   XF[(src*B + b)*256 + nt][kt][lane2*8 + j], lane2 = (n&15) + g*16,
//   value = X[b][c = kt*32 + g*8 + j][nt*16 + (n&15)]
// grid (64, B, 2 src), block 256 (4 waves; wave = 1 ntile)
// ---------------------------------------------------------------------------
__global__ __launch_bounds__(256) void splitX(
    const float* __restrict__ x, const float* __restrict__ xl,
    short* __restrict__ XFh, short* __restrict__ XFl)
{
    int src = blockIdx.z, b = blockIdx.y, bx = blockIdx.x;
    const float* X = src ? xl : x;
    int t = threadIdx.x, wv = t >> 6, ln = t & 63;
    int nt = bx * 4 + wv;
    int n = (nt << 4) + (ln & 15);
    int g = ln >> 4;
    size_t sb = ((size_t)(src * BATCH + b) * 256 + nt) * 2;
    #pragma unroll
    for (int kt = 0; kt < 2; kt++) {
        short8 h, l;
        #pragma unroll
        for (int j = 0; j < 8; j++) {
            float v = X[(size_t)(b * 64 + kt * 32 + g * 8 + j) * HW + n];
            short hh = f2bf(v);
            h[j] = hh;
            l[j] = f2bf(v - bf2f(hh));
        }
        *(short8*)(XFh + (sb + kt) * 512 + (size_t)ln * 8) = h;
        *(short8*)(XFl + (sb + kt) * 512 + (size_t)ln * 8) = l;
    }
}

// ---------------------------------------------------------------------------
// convm: 1x1 convs via 3-term split-bf16 MFMA.
// mode: 0 W_low->XLOW fp32 + PA | 1 W_val->PV | 2 W_mid->XMID
//       3 W_lat->XL2 | 4 W_high->PB
// grid (64, B, 5), block 256 (4 waves; wave = 1 ntile of 16 px, all 64 out-ch)
// ---------------------------------------------------------------------------
__global__ __launch_bounds__(256) void convm(
    const short* __restrict__ XFh, const short* __restrict__ XFl,
    const float* __restrict__ Wlow, const float* __restrict__ blow,
    const float* __restrict__ Wval, const float* __restrict__ bval,
    const float* __restrict__ Wmid, const float* __restrict__ bmid,
    const float* __restrict__ Wlat, const float* __restrict__ blat,
    const float* __restrict__ Whigh, const float* __restrict__ bhigh,
    float* __restrict__ XLOW, float* __restrict__ XMID, float* __restrict__ XL2,
    short* __restrict__ PAh, short* __restrict__ PAl,
    short* __restrict__ PBh, short* __restrict__ PBl,
    short* __restrict__ PVh, short* __restrict__ PVl)
{
    int mode = blockIdx.z, b = blockIdx.y, bx = blockIdx.x;
    const float* W; const float* bias; int src;
    switch (mode) {
        case 0:  W = Wlow;  bias = blow;  src = 0; break;
        case 1:  W = Wval;  bias = bval;  src = 0; break;
        case 2:  W = Wmid;  bias = bmid;  src = 0; break;
        case 3:  W = Wlat;  bias = blat;  src = 1; break;
        default: W = Whigh; bias = bhigh; src = 1; break;
    }
    int t = threadIdx.x, wv = t >> 6, ln = t & 63;
    int row = ln & 15, g = ln >> 4;

    // W A-frags: 4 o-tiles x 2 k-tiles, hi/lo
    short8 Wh[4][2], Wlo[4][2];
    #pragma unroll
    for (int ot = 0; ot < 4; ot++)
        #pragma unroll
        for (int kt = 0; kt < 2; kt++) {
            const float* wp = W + (ot * 16 + row) * 64 + kt * 32 + g * 8;
            short8 h, l;
            #pragma unroll
            for (int j = 0; j < 8; j++) {
                float v = wp[j];
                short hh = f2bf(v);
                h[j] = hh;
                l[j] = f2bf(v - bf2f(hh));
            }
            Wh[ot][kt] = h; Wlo[ot][kt] = l;
        }

    // X B-frags for this wave's ntile
    int nt = bx * 4 + wv;
    size_t xb = ((size_t)(src * BATCH + b) * 256 + nt) * 2;
    short8 Bh[2], Bl[2];
    #pragma unroll
    for (int kt = 0; kt < 2; kt++) {
        Bh[kt] = *(const short8*)(XFh + (xb + kt) * 512 + (size_t)ln * 8);
        Bl[kt] = *(const short8*)(XFl + (xb + kt) * 512 + (size_t)ln * 8);
    }

    // acc[ot]: D[col = n = ln&15][row = o = ot*16 + (ln>>4)*4 + r]
    f32x4 acc[4];
    #pragma unroll
    for (int ot = 0; ot < 4; ot++) {
        #pragma unroll
        for (int r = 0; r < 4; r++) acc[ot][r] = bias[ot * 16 + g * 4 + r];
    }
    #pragma unroll
    for (int ot = 0; ot < 4; ot++)
        #pragma unroll
        for (int kt = 0; kt < 2; kt++) {
            acc[ot] = MFMA(Wh[ot][kt], Bh[kt], acc[ot]);
            acc[ot] = MFMA(Wh[ot][kt], Bl[kt], acc[ot]);
            acc[ot] = MFMA(Wlo[ot][kt], Bh[kt], acc[ot]);
        }

    // LDS bounce tile: Ld[n 0..63][o 0..63], pad 65 (scalar access only)
    __shared__ float Ld[64][65];
    #pragma unroll
    for (int ot = 0; ot < 4; ot++)
        #pragma unroll
        for (int r = 0; r < 4; r++)
            Ld[wv * 16 + (ln & 15)][ot * 16 + g * 4 + r] = acc[ot][r];
    __syncthreads();

    int n0 = bx * 64;
    if (mode == 0 || mode == 2 || mode == 3) {
        float* outp = (mode == 0) ? XLOW : (mode == 2) ? XMID : XL2;
        int n = t >> 2, o0 = (t & 3) * 16;
        float vout[16];
        #pragma unroll
        for (int k = 0; k < 16; k++) vout[k] = Ld[n][o0 + k];
        float* gp = outp + ((size_t)b * HW + n0 + n) * 64 + o0;
        #pragma unroll
        for (int k = 0; k < 4; k++)
            *(float4v*)(gp + k * 4) = *(float4v*)(vout + k * 4);
    }
    if (mode == 0 || mode == 4) {
        // pack A-frag (mode 0: PA, rows=n) or B-frag (mode 4: PB, cols=m) — same transform
        short* Ph = (mode == 0) ? PAh : PBh;
        short* Pl = (mode == 0) ? PAl : PBl;
        #pragma unroll
        for (int kt = 0; kt < 2; kt++) {
            short8 h, l;
            #pragma unroll
            for (int j = 0; j < 8; j++) {
                float v = Ld[wv * 16 + (ln & 15)][kt * 32 + g * 8 + j];
                short hh = f2bf(v);
                h[j] = hh;
                l[j] = f2bf(v - bf2f(hh));
            }
            size_t blob = (((size_t)b * 256 + bx * 4 + wv) * 2 + kt) * 512 + (size_t)ln * 8;
            *(short8*)(Ph + blob) = h;
            *(short8*)(Pl + blob) = l;
        }
    }
    if (mode == 1) {
        // PV: B-frag with k=m, col=c. Block covers 2 ktm tiles (m-of-32).
        int ktm_l = wv >> 1;
        int ct0 = (wv & 1) * 2;
        #pragma unroll
        for (int cc = 0; cc < 2; cc++) {
            int ct = ct0 + cc;
            int c = ct * 16 + (ln & 15);
            short8 h, l;
            #pragma unroll
            for (int j = 0; j < 8; j++) {
                float v = Ld[ktm_l * 32 + g * 8 + j][c];
                short hh = f2bf(v);
                h[j] = hh;
                l[j] = f2bf(v - bf2f(hh));
            }
            size_t blob = (((size_t)b * 128 + bx * 2 + ktm_l) * 4 + ct) * 512 + (size_t)ln * 8;
            *(short8*)(PVh + blob) = h;
            *(short8*)(PVl + blob) = l;
        }
    }
}

// ---------------------------------------------------------------------------
// zpass: Z[m] partials = sum_n exp(S[n,m]) over n-chunk of 1024 (unchanged).
// ---------------------------------------------------------------------------
__global__ __launch_bounds__(256) void zpass(
    const short* __restrict__ PAh, const short* __restrict__ PAl,
    const short* __restrict__ PBh, const short* __restrict__ PBl,
    float* __restrict__ Zp)
{
    int b = blockIdx.z, nc = blockIdx.y, mchunk = blockIdx.x;
    int t = threadIdx.x, wv = t >> 6, ln = t & 63;
    short8 bh[4][2], bl[4][2];
    #pragma unroll
    for (int msub = 0; msub < 4; msub++)
        #pragma unroll
        for (int kt = 0; kt < 2; kt++) {
            size_t o = ((size_t)(b * 256 + mchunk * 4 + msub) * 2 + kt) * 512 + ln * 8;
            bh[msub][kt] = *(const short8*)(PBh + o);
            bl[msub][kt] = *(const short8*)(PBl + o);
        }
    float zacc[4] = {0.f, 0.f, 0.f, 0.f};
    for (int s = 0; s < 16; s++) {
        int nt = nc * 64 + s * 4 + wv;
        size_t ab = ((size_t)(b * 256 + nt) * 2) * 512 + ln * 8;
        short8 ah0 = *(const short8*)(PAh + ab);
        short8 ah1 = *(const short8*)(PAh + ab + 512);
        short8 al0 = *(const short8*)(PAl + ab);
        short8 al1 = *(const short8*)(PAl + ab + 512);
        #pragma unroll
        for (int msub = 0; msub < 4; msub++) {
            f32x4 acc = {0.f, 0.f, 0.f, 0.f};
            acc = MFMA(ah0, bh[msub][0], acc);
            acc = MFMA(ah1, bh[msub][1], acc);
            acc = MFMA(ah0, bl[msub][0], acc);
            acc = MFMA(ah1, bl[msub][1], acc);
            acc = MFMA(al0, bh[msub][0], acc);
            acc = MFMA(al1, bh[msub][1], acc);
            float z = __expf(acc[0]) + __expf(acc[1]) + __expf(acc[2]) + __expf(acc[3]);
            z += __shfl_xor(z, 16, 64);
            z += __shfl_xor(z, 32, 64);
            zacc[msub] += z;
        }
    }
    __shared__ float sZ[4][64];
    if (ln < 16) {
        #pragma unroll
        for (int msub = 0; msub < 4; msub++) sZ[wv][msub * 16 + ln] = zacc[msub];
    }
    __syncthreads();
    if (t < 64) {
        float z = sZ[0][t] + sZ[1][t] + sZ[2][t] + sZ[3][t];
        Zp[((size_t)(b * 4 + nc)) * 4096 + mchunk * 64 + t] = z;
    }
}

__global__ __launch_bounds__(256) void zmerge(
    const float* __restrict__ Zp, float* __restrict__ Zi)
{
    int gi = blockIdx.x * 256 + threadIdx.x;  // 0..16383
    int b = gi >> 12, m = gi & 4095;
    float z = 0.f;
    #pragma unroll
    for (int nc2 = 0; nc2 < 4; nc2++) z += Zp[((size_t)(b * 4 + nc2)) * 4096 + m];
    Zi[gi] = 1.f / z;
}

// ---------------------------------------------------------------------------
// epass3: partial E over an m-segment of 1024 (unchanged from R4).
// ---------------------------------------------------------------------------
__global__ __launch_bounds__(512) void epass3(
    const short* __restrict__ PAh, const short* __restrict__ PAl,
    const short* __restrict__ PBh, const short* __restrict__ PBl,
    const short* __restrict__ PVh, const short* __restrict__ PVl,
    const float* __restrict__ Zi, float* __restrict__ Ep)
{
    int b = blockIdx.z, mseg = blockIdx.y, nb = blockIdx.x;
    int t = threadIdx.x, wv = t >> 6, ln = t & 63;
    int lnm = ln & 15, lnr = ln >> 4;

    __shared__ __align__(16) short sB[2][2][4096];      // 32 KB [buf][hi/lo]
    __shared__ __align__(16) short sV[2][2][4096];      // 32 KB
    __shared__ __align__(16) short sW[8][2][2][2][512]; // 64 KB [wave][rt][hl][kt]
    __shared__ float sZi[1024];                          // 4 KB

    int nt = nb * 16 + wv * 2;
    short8 Ah[2][2], Al[2][2];
    #pragma unroll
    for (int rt = 0; rt < 2; rt++)
        #pragma unroll
        for (int kt = 0; kt < 2; kt++) {
            size_t base = ((size_t)(b * 256 + nt + rt) * 2 + kt) * 512 + ln * 8;
            Ah[rt][kt] = *(const short8*)(PAh + base);
            Al[rt][kt] = *(const short8*)(PAl + base);
        }
    sZi[t]       = Zi[b * 4096 + mseg * 1024 + t];
    sZi[t + 512] = Zi[b * 4096 + mseg * 1024 + t + 512];
    __syncthreads();

    f32x4 acc_e[2][4];
    #pragma unroll
    for (int rt = 0; rt < 2; rt++)
        #pragma unroll
        for (int ct = 0; ct < 4; ct++) acc_e[rt][ct] = (f32x4){0.f, 0.f, 0.f, 0.f};

    const int mc0 = mseg * 16;
    #define STAGE(bufi, ii) { \
        size_t bb = (size_t)b * 262144 + (size_t)(mc0 + (ii)) * 4096 + t * 8; \
        gld16(PBh + bb, &sB[bufi][0][wv * 512]); \
        gld16(PBl + bb, &sB[bufi][1][wv * 512]); \
        gld16(PVh + bb, &sV[bufi][0][wv * 512]); \
        gld16(PVl + bb, &sV[bufi][1][wv * 512]); }

    STAGE(0, 0);
    for (int i = 0; i < 16; i++) {
        int cur = i & 1;
        __builtin_amdgcn_s_barrier();
        if (i < 15) {
            STAGE(cur ^ 1, i + 1);
            asm volatile("s_waitcnt vmcnt(4)" ::: "memory");
        } else {
            asm volatile("s_waitcnt vmcnt(0)" ::: "memory");
        }
        __builtin_amdgcn_sched_barrier(0);

        #pragma unroll
        for (int msub = 0; msub < 4; msub++) {
            const short8 bh0 = *(const short8*)&sB[cur][0][(msub * 2 + 0) * 512 + ln * 8];
            const short8 bh1 = *(const short8*)&sB[cur][0][(msub * 2 + 1) * 512 + ln * 8];
            const short8 bl0 = *(const short8*)&sB[cur][1][(msub * 2 + 0) * 512 + ln * 8];
            const short8 bl1 = *(const short8*)&sB[cur][1][(msub * 2 + 1) * 512 + ln * 8];
            float zi = sZi[i * 64 + msub * 16 + lnm];
            int m = msub * 16 + lnm;
            int ktw = m >> 5, j = m & 7, g = (m >> 3) & 3;
            #pragma unroll
            for (int rt = 0; rt < 2; rt++) {
                f32x4 acc = {0.f, 0.f, 0.f, 0.f};
                acc = MFMA(Ah[rt][0], bh0, acc);
                acc = MFMA(Ah[rt][1], bh1, acc);
                acc = MFMA(Ah[rt][0], bl0, acc);
                acc = MFMA(Ah[rt][1], bl1, acc);
                acc = MFMA(Al[rt][0], bh0, acc);
                acc = MFMA(Al[rt][1], bh1, acc);
                #pragma unroll
                for (int r = 0; r < 4; r++) {
                    float w = __expf(acc[r]) * zi;
                    short wh = f2bf(w);
                    short wl2 = f2bf(w - bf2f(wh));
                    int lane2 = (lnr * 4 + r) + g * 16;
                    int slot = lane2 ^ (lane2 >> 3);
                    sW[wv][rt][0][ktw][slot * 8 + j] = wh;
                    sW[wv][rt][1][ktw][slot * 8 + j] = wl2;
                }
            }
        }
        int rslot = (ln ^ (ln >> 3)) * 8;
        #pragma unroll
        for (int kt = 0; kt < 2; kt++) {
            const short8 w0h = *(const short8*)&sW[wv][0][0][kt][rslot];
            const short8 w0l = *(const short8*)&sW[wv][0][1][kt][rslot];
            const short8 w1h = *(const short8*)&sW[wv][1][0][kt][rslot];
            const short8 w1l = *(const short8*)&sW[wv][1][1][kt][rslot];
            #pragma unroll
            for (int ct = 0; ct < 4; ct++) {
                const short8 vh = *(const short8*)&sV[cur][0][(kt * 4 + ct) * 512 + ln * 8];
                const short8 vl = *(const short8*)&sV[cur][1][(kt * 4 + ct) * 512 + ln * 8];
                acc_e[0][ct] = MFMA(w0h, vh, acc_e[0][ct]);
                acc_e[0][ct] = MFMA(w0h, vl, acc_e[0][ct]);
                acc_e[0][ct] = MFMA(w0l, vh, acc_e[0][ct]);
                acc_e[1][ct] = MFMA(w1h, vh, acc_e[1][ct]);
                acc_e[1][ct] = MFMA(w1h, vl, acc_e[1][ct]);
                acc_e[1][ct] = MFMA(w1l, vh, acc_e[1][ct]);
            }
        }
    }
    #undef STAGE

    float* ep = Ep + ((size_t)mseg * BATCH + b) * HW * 64;
    #pragma unroll
    for (int rt = 0; rt < 2; rt++) {
        int n0 = (nt + rt) * 16 + lnr * 4;
        #pragma unroll
        for (int ct = 0; ct < 4; ct++) {
            #pragma unroll
            for (int r = 0; r < 4; r++)
                ep[(size_t)(n0 + r) * 64 + ct * 16 + lnm] = acc_e[rt][ct][r];
        }
    }
}

// ---------------------------------------------------------------------------
// econv5: E1 = sum(4 partials) + XLOW (residual), then E2 = W_ec * E1 + b_ec
// ---------------------------------------------------------------------------
__global__ __launch_bounds__(256) void econv5(
    const float* __restrict__ Ep, const float* __restrict__ XLOW,
    const float* __restrict__ W, const float* __restrict__ bias,
    float* __restrict__ E2)
{
    const size_t SEG = (size_t)BATCH * HW * 64;
    int b = blockIdx.y, n0 = blockIdx.x * 64, t = threadIdx.x;
    __shared__ float Wl[64][64];
    __shared__ float El[64][65];
    for (int i = t; i < 4096; i += 256) Wl[i >> 6][i & 63] = W[i];
    for (int i = t; i < 4096; i += 256) {
        int nl = i >> 6, c = i & 63;
        size_t idx = ((size_t)b * HW + n0 + nl) * 64 + c;
        El[nl][c] = XLOW[idx] + Ep[idx] + Ep[SEG + idx] + Ep[2 * SEG + idx] + Ep[3 * SEG + idx];
    }
    __syncthreads();
    int nl = t & 63, og = t >> 6;
    for (int k = 0; k < 16; k++) {
        int o = og * 16 + k;
        float a0 = bias[o], a1 = 0.f, a2 = 0.f, a3 = 0.f;
        #pragma unroll
        for (int c = 0; c < 64; c += 4) {
            a0 += Wl[o][c]     * El[nl][c];
            a1 += Wl[o][c + 1] * El[nl][c + 1];
            a2 += Wl[o][c + 2] * El[nl][c + 2];
            a3 += Wl[o][c + 3] * El[nl][c + 3];
        }
        E2[((size_t)b * 64 + o) * HW + n0 + nl] = (a0 + a1) + (a2 + a3);
    }
}

// ---------------------------------------------------------------------------
// tmat: T[b][c][d] = sum_n E2[b][c][n] * XL2[b][n][d]; block 1024
// ---------------------------------------------------------------------------
__global__ __launch_bounds__(1024) void tmat(
    const float* __restrict__ E2, const float* __restrict__ XL2, float* __restrict__ T)
{
    int b = blockIdx.y, c = blockIdx.x, t = threadIdx.x;
    int d = t & 63, nl = t >> 6;   // nl 0..15
    const float* e = E2 + ((size_t)b * 64 + c) * HW;
    const float* x2 = XL2 + (size_t)b * HW * 64;
    float a0 = 0.f, a1 = 0.f;
    #pragma unroll 4
    for (int k = 0; k < 256; k += 2) {
        int na = k * 16 + nl, nb2 = na + 16;
        a0 += e[na] * x2[(size_t)na * 64 + d];
        a1 += e[nb2] * x2[(size_t)nb2 * 64 + d];
    }
    __shared__ float red[16][64];
    red[nl][d] = a0 + a1;
    __syncthreads();
    if (t < 64) {
        float s = 0.f;
        #pragma unroll
        for (int j = 0; j < 16; j++) s += red[j][t];
        T[((size_t)b * 64 + c) * 64 + t] = s;
    }
}

// softmax over c for each (b, d)
__global__ __launch_bounds__(64) void softT(
    const float* __restrict__ T, float* __restrict__ Ts)
{
    int d = blockIdx.x, b = blockIdx.y, c = threadIdx.x;
    float v = T[((size_t)b * 64 + c) * 64 + d];
    float M = v;
    #pragma unroll
    for (int o = 32; o > 0; o >>= 1) M = fmaxf(M, __shfl_xor(M, o, 64));
    float ez = __expf(v - M);
    float Z = ez;
    #pragma unroll
    for (int o = 32; o > 0; o >>= 1) Z += __shfl_xor(Z, o, 64);
    Ts[((size_t)b * 64 + c) * 64 + d] = ez / Z;
}

// out[b][d][n] = sum_c XMID[b][n][c] * Ts[b][c][d]
__global__ __launch_bounds__(256) void outk(
    const float* __restrict__ XMID, const float* __restrict__ Ts, float* __restrict__ out)
{
    int b = blockIdx.y, n0 = blockIdx.x * 64, t = threadIdx.x;
    __shared__ float Xm[64][65];
    __shared__ float Tl[64][64];
    for (int i = t; i < 4096; i += 256) {
        int nl = i >> 6, c = i & 63;
        Xm[nl][c] = XMID[((size_t)b * HW + n0 + nl) * 64 + c];
    }
    for (int i = t; i < 4096; i += 256) Tl[i >> 6][i & 63] = Ts[(size_t)b * 4096 + i];
    __syncthreads();
    int nl = t & 63, dg = t >> 6;
    float accs[16];
    #pragma unroll
    for (int k = 0; k < 16; k++) accs[k] = 0.f;
    for (int c = 0; c < 64; c++) {
        float xv = Xm[nl][c];
        #pragma unroll
        for (int k = 0; k < 16; k++) accs[k] += xv * Tl[c][dg * 16 + k];
    }
    #pragma unroll
    for (int k = 0; k < 16; k++) {
        int d = dg * 16 + k;
        out[((size_t)b * 64 + d) * HW + n0 + nl] = accs[k];
    }
}

// ---------------------------------------------------------------------------
extern "C" void kernel_launch(void* const* d_in, const int* in_sizes, int n_in,
                              void* d_out, int out_size, void* d_ws, size_t ws_size,
                              hipStream_t stream)
{
    const float* x_latter = (const float*)d_in[0];
    const float* x        = (const float*)d_in[1];
    const float* W_high = (const float*)d_in[2];  const float* b_high = (const float*)d_in[3];
    const float* W_low  = (const float*)d_in[4];  const float* b_low  = (const float*)d_in[5];
    const float* W_val  = (const float*)d_in[6];  const float* b_val  = (const float*)d_in[7];
    const float* W_ec   = (const float*)d_in[8];  const float* b_ec   = (const float*)d_in[9];
    const float* W_mid  = (const float*)d_in[10]; const float* b_mid  = (const float*)d_in[11];
    const float* W_lat  = (const float*)d_in[12]; const float* b_lat  = (const float*)d_in[13];
    float* outp = (float*)d_out;

    const size_t MAT = (size_t)BATCH * CH * HW;  // 1,048,576 elements
    float* ws = (float*)d_ws;
    size_t off = 0;
    float* XLOW = ws + off; off += MAT;              // [b][n][c]
    float* XMID = ws + off; off += MAT;              // [b][n][c]
    float* XL2  = ws + off; off += MAT;              // [b][n][d]
    float* Ep   = ws + off; off += 4 * MAT;          // 4 m-segment partials of E
    float* Zp   = ws + off; off += (size_t)BATCH * 4 * HW;
    float* Zic  = ws + off; off += (size_t)BATCH * HW;
    float* T    = ws + off; off += (size_t)BATCH * 64 * 64;
    float* Ts   = ws + off; off += (size_t)BATCH * 64 * 64;
    short* sp = (short*)(ws + off);
    short* PAh = sp; sp += MAT;   // packed A-frags of XLOW (hi)
    short* PAl = sp; sp += MAT;
    short* PBh = sp; sp += MAT;   // packed B-frags of XLHI
    short* PBl = sp; sp += MAT;
    short* PVh = sp; sp += MAT;   // packed B-frags of V
    short* PVl = sp; sp += MAT;
    float* E2  = (float*)PAh;     // alias: PA dead after epass3
    // XF blobs alias Ep (Ep only written by epass3, after convm is done)
    short* XFh = (short*)Ep;                 // 2 src * 4 b * 262144 shorts = 4MB
    short* XFl = XFh + 2 * BATCH * 262144;   // 4MB

    splitX<<<dim3(64, BATCH, 2), 256, 0, stream>>>(x, x_latter, XFh, XFl);
    convm<<<dim3(64, BATCH, 5), 256, 0, stream>>>(
        XFh, XFl, W_low, b_low, W_val, b_val, W_mid, b_mid, W_lat, b_lat,
        W_high, b_high, XLOW, XMID, XL2, PAh, PAl, PBh, PBl, PVh, PVl);
    zpass<<<dim3(64, 4, BATCH), 256, 0, stream>>>(PAh, PAl, PBh, PBl, Zp);
    zmerge<<<dim3(64), 256, 0, stream>>>(Zp, Zic);
    epass3<<<dim3(16, 4, BATCH), 512, 0, stream>>>(PAh, PAl, PBh, PBl, PVh, PVl, Zic, Ep);
    econv5<<<dim3(64, BATCH), 256, 0, stream>>>(Ep, XLOW, W_ec, b_ec, E2);
    tmat<<<dim3(64, BATCH), 1024, 0, stream>>>(E2, XL2, T);
    softT<<<dim3(64, BATCH), 64, 0, stream>>>(T, Ts);
    outk<<<dim3(64, BATCH), 256, 0, stream>>>(XMID, Ts, outp);
}